// Round 12
// baseline (223.124 us; speedup 1.0000x reference)
//
#include <hip/hip_runtime.h>
#include <math.h>

typedef __attribute__((ext_vector_type(4))) float  f32x4;
typedef __attribute__((ext_vector_type(8))) short  s16x8;
typedef __attribute__((ext_vector_type(4))) short  s16x4;

#define BN_EPS 1e-3f
#define AS1 const __attribute__((address_space(1))) void*
#define AS3 __attribute__((address_space(3))) void*

static constexpr int    CC    = 256;
static constexpr int    NVOX  = 32768;
static constexpr int    BATCH = 2;
static constexpr int    MTOT  = BATCH * NVOX;              // 65536 rows
static constexpr size_t ELEM_BR = (size_t)MTOT * CC;       // 16,777,216 per branch
static constexpr size_t SZ_BR   = ELEM_BR * 2;             // bf16 bytes
// workspace layout
static constexpr size_t WS_Q   = 0;
static constexpr size_t WS_K   = WS_Q  + SZ_BR;
static constexpr size_t WS_J   = WS_K  + SZ_BR;
static constexpr size_t WS_V   = WS_J  + SZ_BR;
static constexpr size_t WS_M1  = WS_V  + SZ_BR;                       // f32 [2][256][256]
static constexpr size_t WS_M2  = WS_M1 + (size_t)BATCH*CC*CC*4;
static constexpr size_t WS_AFF = WS_M2 + (size_t)BATCH*CC*CC*4;       // bf16 [2][256][256]
static constexpr size_t WS_WT  = WS_AFF + (size_t)BATCH*CC*CC*2;      // bf16 Wt[4][cout][cin]
static constexpr size_t WS_AB  = WS_WT + (size_t)4*CC*CC*2;           // f32 alpha[1024], beta[1024]
// WS_P dual-use: [k0b..k1b] bf16 Xbf[65536][256]; [k2..k25] bf16 partials [4][64][65536]
static constexpr size_t WS_P   = WS_AB + 2048*4;
static constexpr size_t WS_NEED_PART = WS_P + (size_t)4*64*65536*2;   // ~162 MiB

__device__ __forceinline__ short f2bf(float f) {
  union { float f; unsigned u; } v; v.f = f;
  unsigned u = v.u + 0x7FFFu + ((v.u >> 16) & 1u);   // RNE
  return (short)(u >> 16);
}
__device__ __forceinline__ float bf2f(short s) {
  union { unsigned u; float f; } v; v.u = ((unsigned)(unsigned short)s) << 16;
  return v.f;
}
__device__ __forceinline__ unsigned long long packBN(f32x4 a, f32x4 al, f32x4 be) {
  union { s16x4 v; unsigned long long u; } c;
  #pragma unroll
  for (int ii = 0; ii < 4; ++ii) {
    float yv = al[ii] * a[ii] + be[ii];
    c.v[ii] = f2bf(yv > 0.f ? yv : 0.f);
  }
  return c.u;
}

// ---------------- k0: prep — weights bf16, fold BN, zero m1/m2 ----------------
__global__ __launch_bounds__(256) void k0_prep(
    const float* __restrict__ conv_w, const float* __restrict__ conv_b,
    const float* __restrict__ bn_s, const float* __restrict__ bn_o,
    const float* __restrict__ bn_m, const float* __restrict__ bn_v,
    char* __restrict__ ws)
{
  int t = blockIdx.x * 256 + threadIdx.x;              // 0..262143
  ((float*)(ws + WS_M1))[t] = 0.f;
  int f = t >> 16, rem = t & 65535;
  int cin = rem >> 8, cout = rem & 255;
  ((short*)(ws + WS_WT))[f*65536 + cout*256 + cin] = f2bf(conv_w[t]);
  if (t < 1024) {
    float alpha = bn_s[t] * rsqrtf(bn_v[t] + BN_EPS);
    float beta  = alpha * (conv_b[t] - bn_m[t]) + bn_o[t];
    float* ab = (float*)(ws + WS_AB);
    ab[t] = alpha; ab[1024 + t] = beta;
  }
}

// ---------------- k0b: x f32 -> bf16 (Xbf at WS_P) ---------------------------
__global__ __launch_bounds__(256) void k0b_convert(
    const float* __restrict__ x, char* __restrict__ ws)
{
  int t = blockIdx.x * 256 + threadIdx.x;              // 0..262143
  short* Xbf = (short*)(ws + WS_P);
  #pragma unroll
  for (int it = 0; it < 16; ++it) {
    int f4 = t + 262144 * it;                          // 4,194,304 float4s
    const float4 v = *(const float4*)(x + (size_t)f4 * 4);
    s16x4 s; s[0]=f2bf(v.x); s[1]=f2bf(v.y); s[2]=f2bf(v.z); s[3]=f2bf(v.w);
    *(s16x4*)&Xbf[(size_t)f4 * 4] = s;
  }
}

// ---------------- k1b: branches GEMM (k2-shaped) ------------------------------
// Block = 128 rows x 128 couts, 256 thr / 4 waves (2x2, wave 64x64, acc[4][4]).
// k=256 streamed as 4 dbuf k-tiles [128][64] via global_load_lds, swizzle
// u^(r&7) both sides. 5 barriers/block. XCD-grouped bid: the 8 cout-blocks of
// one row-tile share an XCD -> A-tile L2-shared (HBM reads A once).
__global__ __launch_bounds__(256, 2) void k1b_gemm(char* __restrict__ ws)
{
  __shared__ short Aa[2][128 * 64];   // 2 x 16KB
  __shared__ short Wl[2][128 * 64];   // 2 x 16KB

  const int tid = threadIdx.x;
  const int bid = blockIdx.x;                  // 4096
  const int r8 = bid & 7, q = bid >> 3;
  const int cg = q & 7, rt = (q >> 3) * 8 + r8;   // rt 0..511, cg 0..7
  const int f  = cg >> 1, c0 = (cg & 1) * 128;

  const short* Xbf = (const short*)(ws + WS_P);
  const short* Wf  = (const short*)(ws + WS_WT) + f * 65536;
  const float* ab  = (const float*)(ws + WS_AB);

  const int lane = tid & 63, wid = tid >> 6;
  const int wm = wid >> 1, wn = wid & 1;       // 2x2 waves
  const int lr = lane & 15, lg = lane >> 4;

  // stage kt=0
  #pragma unroll
  for (int i = 0; i < 4; ++i) {
    int slot = i * 256 + tid;                  // 1024 16B slots per tile
    int r = slot >> 3, u = slot & 7, us = u ^ (r & 7);
    __builtin_amdgcn_global_load_lds(
        (AS1)(Xbf + (size_t)(rt*128 + r) * 256 + us * 8),
        (AS3)(&Aa[0][(i * 256 + wid * 64) * 8]), 16, 0, 0);
    __builtin_amdgcn_global_load_lds(
        (AS1)(Wf + (c0 + r) * 256 + us * 8),
        (AS3)(&Wl[0][(i * 256 + wid * 64) * 8]), 16, 0, 0);
  }
  __syncthreads();

  f32x4 acc[4][4];
  #pragma unroll
  for (int a = 0; a < 4; ++a)
    #pragma unroll
    for (int c = 0; c < 4; ++c) { f32x4 z = {0.f,0.f,0.f,0.f}; acc[a][c] = z; }

  for (int kt = 0; kt < 4; ++kt) {
    const int cur = kt & 1;
    if (kt < 3) {
      const int ko = (kt + 1) * 64;
      const int nxt = cur ^ 1;
      #pragma unroll
      for (int i = 0; i < 4; ++i) {
        int slot = i * 256 + tid;
        int r = slot >> 3, u = slot & 7, us = u ^ (r & 7);
        __builtin_amdgcn_global_load_lds(
            (AS1)(Xbf + (size_t)(rt*128 + r) * 256 + ko + us * 8),
            (AS3)(&Aa[nxt][(i * 256 + wid * 64) * 8]), 16, 0, 0);
        __builtin_amdgcn_global_load_lds(
            (AS1)(Wf + (c0 + r) * 256 + ko + us * 8),
            (AS3)(&Wl[nxt][(i * 256 + wid * 64) * 8]), 16, 0, 0);
      }
    }
    #pragma unroll
    for (int ks = 0; ks < 2; ++ks) {
      const int ua = ks * 4 + lg;
      s16x8 af[4], wf[4];
      #pragma unroll
      for (int mi = 0; mi < 4; ++mi) {
        int r = wm*64 + mi*16 + lr;
        af[mi] = *(const s16x8*)&Aa[cur][r * 64 + (ua ^ (r & 7)) * 8];
      }
      #pragma unroll
      for (int nj = 0; nj < 4; ++nj) {
        int c = wn*64 + nj*16 + lr;
        wf[nj] = *(const s16x8*)&Wl[cur][c * 64 + (ua ^ (c & 7)) * 8];
      }
      #pragma unroll
      for (int mi = 0; mi < 4; ++mi)
        #pragma unroll
        for (int nj = 0; nj < 4; ++nj)
          acc[mi][nj] = __builtin_amdgcn_mfma_f32_16x16x32_bf16(
              wf[nj], af[mi], acc[mi][nj], 0, 0, 0);  // cout<-lg*4+ii, row<-lr
    }
    __syncthreads();
  }

  // epilogue: BN+ReLU, shfl-pack (proven in r11), 16B/lane -> 64B row segments
  short* Yf = (short*)(ws + (size_t)f * SZ_BR);
  const int cwb = c0 + wn * 64;                // cout base of this wave
  #pragma unroll
  for (int mi = 0; mi < 4; ++mi) {
    const size_t row = (size_t)(rt*128 + wm*64 + mi*16 + lr);
    #pragma unroll
    for (int njp = 0; njp < 4; njp += 2) {
      const int ca = cwb + njp*16 + lg*4;
      const f32x4 al0 = *(const f32x4*)&ab[f*256 + ca];
      const f32x4 be0 = *(const f32x4*)&ab[1024 + f*256 + ca];
      const f32x4 al1 = *(const f32x4*)&ab[f*256 + ca + 16];
      const f32x4 be1 = *(const f32x4*)&ab[1024 + f*256 + ca + 16];
      unsigned long long p0 = packBN(acc[mi][njp],     al0, be0);
      unsigned long long p1 = packBN(acc[mi][njp + 1], al1, be1);
      unsigned long long q0 = __shfl_xor(p0, 16, 64);
      unsigned long long q1 = __shfl_xor(p1, 16, 64);
      ulonglong2 ch0, ch1;
      if (lg & 1) { ch0.x = q0; ch0.y = p0; ch1.x = q1; ch1.y = p1; }
      else        { ch0.x = p0; ch0.y = q0; ch1.x = p1; ch1.y = q1; }
      ulonglong2 sel = (lg & 1) ? ch1 : ch0;
      const int cout_s = cwb + njp*16 + (lg & 1) * 16 + (lg >> 1) * 8;
      *(ulonglong2*)&Yf[row * 256 + cout_s] = sel;
    }
  }
}

// ---------------- k1: fallback (round-4 structure) ----------------------------
__global__ __launch_bounds__(256, 2) void k1_branches(
    const float* __restrict__ x, char* __restrict__ ws)
{
  __shared__ short As[64 * 256];
  __shared__ short Bs[64 * 256];
  __shared__ short Rs[64][72];

  const int tid = threadIdx.x;
  const int m0  = blockIdx.x * 64;
  const int lane = tid & 63, wid = tid >> 6;
  const int wm = wid >> 1, wn = wid & 1;
  const int lr = lane & 15, lg = lane >> 4;

  const short* Wt = (const short*)(ws + WS_WT);
  const float* ab = (const float*)(ws + WS_AB);

  #pragma unroll
  for (int it = 0; it < 16; ++it) {
    int idx = tid + 256 * it;
    int r = idx >> 6, c4 = (idx & 63) << 2;
    const float4 v = *(const float4*)(x + (size_t)(m0 + r) * 256 + c4);
    s16x4 s; s[0]=f2bf(v.x); s[1]=f2bf(v.y); s[2]=f2bf(v.z); s[3]=f2bf(v.w);
    int u = c4 >> 3;
    int swz = ((u ^ ((r & 7) << 2)) << 3) | (c4 & 7);
    *(s16x4*)&As[r * 256 + swz] = s;
  }
  {
    #pragma unroll
    for (int i = 0; i < 8; ++i) {
      int slot = i * 256 + tid;
      int cout = slot >> 5, u = slot & 31;
      int usrc = u ^ ((cout & 7) << 2);
      __builtin_amdgcn_global_load_lds(
          (AS1)(Wt + cout * 256 + usrc * 8),
          (AS3)(Bs + (size_t)(i * 256 + wid * 64) * 8), 16, 0, 0);
    }
  }
  __syncthreads();

  for (int nt = 0; nt < 16; ++nt) {
    const int f  = nt >> 2;
    const int c0 = (nt & 3) * 64;
    f32x4 acc[2][2];
    #pragma unroll
    for (int a = 0; a < 2; ++a)
      #pragma unroll
      for (int b = 0; b < 2; ++b) { f32x4 z = {0.f,0.f,0.f,0.f}; acc[a][b] = z; }
    #pragma unroll
    for (int k0 = 0; k0 < 8; ++k0) {
      const int ua = k0 * 4 + lg;
      s16x8 af[2], bf[2];
      #pragma unroll
      for (int mi = 0; mi < 2; ++mi) {
        int r = wm*32 + mi*16 + lr;
        af[mi] = *(const s16x8*)&As[r * 256 + (ua ^ ((r & 7) << 2)) * 8];
      }
      #pragma unroll
      for (int nj = 0; nj < 2; ++nj) {
        int c = wn*32 + nj*16 + lr;
        bf[nj] = *(const s16x8*)&Bs[c * 256 + (ua ^ ((c & 7) << 2)) * 8];
      }
      #pragma unroll
      for (int mi = 0; mi < 2; ++mi)
        #pragma unroll
        for (int nj = 0; nj < 2; ++nj)
          acc[mi][nj] = __builtin_amdgcn_mfma_f32_16x16x32_bf16(
              bf[nj], af[mi], acc[mi][nj], 0, 0, 0);
    }
    __syncthreads();
    if (nt < 15) {
      const int fn  = (nt + 1) >> 2;
      const int c0n = ((nt + 1) & 3) * 64;
      const short* Wfp = Wt + fn * 65536 + c0n * 256;
      #pragma unroll
      for (int i = 0; i < 8; ++i) {
        int slot = i * 256 + tid;
        int cout = slot >> 5, u = slot & 31;
        int usrc = u ^ ((cout & 7) << 2);
        __builtin_amdgcn_global_load_lds(
            (AS1)(Wfp + cout * 256 + usrc * 8),
            (AS3)(Bs + (size_t)(i * 256 + wid * 64) * 8), 16, 0, 0);
      }
    }
    #pragma unroll
    for (int nj = 0; nj < 2; ++nj) {
      int c4b = c0 + wn*32 + nj*16 + lg*4;
      const f32x4 al = *(const f32x4*)&ab[f*256 + c4b];
      const f32x4 be = *(const f32x4*)&ab[1024 + f*256 + c4b];
      #pragma unroll
      for (int mi = 0; mi < 2; ++mi) {
        s16x4 s;
        #pragma unroll
        for (int ii = 0; ii < 4; ++ii) {
          float yv = al[ii] * acc[mi][nj][ii] + be[ii];
          yv = yv > 0.f ? yv : 0.f;
          s[ii] = f2bf(yv);
        }
        *(s16x4*)&Rs[wm*32 + mi*16 + lr][wn*32 + nj*16 + lg*4] = s;
      }
    }
    __syncthreads();
    short* Yf = (short*)(ws + (size_t)f * SZ_BR);
    #pragma unroll
    for (int it = 0; it < 2; ++it) {
      int idx = tid + 256 * it;
      int r = idx >> 3, c8 = (idx & 7) << 3;
      *(s16x8*)&Yf[(size_t)(m0 + r) * 256 + c0 + c8] = *(const s16x8*)&Rs[r][c8];
    }
  }
}

// ---------------- k2: m1 = K*Q^T, m2 = K*J^T ---------------------------------
template<int PART>
__global__ __launch_bounds__(512, 2) void k2_m1m2(char* __restrict__ ws)
{
  __shared__ short Ks[2][16384];
  __shared__ short Xs[2][16384];

  const int tid = threadIdx.x;
  const int chunk = blockIdx.x;
  const int mat = blockIdx.y;
  const int b   = blockIdx.z;
  const size_t boff = (size_t)b * NVOX * CC;
  const short* Km = (const short*)(ws + WS_K) + boff;
  const short* Xm = (const short*)(ws + (mat ? WS_J : WS_Q)) + boff;

  const int lane = tid & 63, wid = tid >> 6;
  const int wm = wid >> 1, wn = wid & 1;
  const int lr = lane & 15, lg = lane >> 4;

  f32x4 acc[4][8];
  #pragma unroll
  for (int a = 0; a < 4; ++a)
    #pragma unroll
    for (int c = 0; c < 8; ++c) { f32x4 z = {0.f,0.f,0.f,0.f}; acc[a][c] = z; }

  {
    const int n0 = chunk * 512;
    #pragma unroll
    for (int i = 0; i < 4; ++i) {
      int slot = i * 512 + tid;
      int r = slot >> 3, u = slot & 7;
      int usrc = u ^ (r & 7);
      const size_t so = (size_t)r * NVOX + n0 + usrc * 8;
      __builtin_amdgcn_global_load_lds((AS1)(Km + so),
          (AS3)(Ks[0] + (size_t)(i * 512 + wid * 64) * 8), 16, 0, 0);
      __builtin_amdgcn_global_load_lds((AS1)(Xm + so),
          (AS3)(Xs[0] + (size_t)(i * 512 + wid * 64) * 8), 16, 0, 0);
    }
  }
  __syncthreads();

  for (int t = 0; t < 8; ++t) {
    const int cur = t & 1;
    if (t < 7) {
      const int n0n = chunk * 512 + (t + 1) * 64;
      const int nxt = cur ^ 1;
      #pragma unroll
      for (int i = 0; i < 4; ++i) {
        int slot = i * 512 + tid;
        int r = slot >> 3, u = slot & 7;
        int usrc = u ^ (r & 7);
        const size_t so = (size_t)r * NVOX + n0n + usrc * 8;
        __builtin_amdgcn_global_load_lds((AS1)(Km + so),
            (AS3)(Ks[nxt] + (size_t)(i * 512 + wid * 64) * 8), 16, 0, 0);
        __builtin_amdgcn_global_load_lds((AS1)(Xm + so),
            (AS3)(Xs[nxt] + (size_t)(i * 512 + wid * 64) * 8), 16, 0, 0);
      }
    }
    #pragma unroll
    for (int ks = 0; ks < 2; ++ks) {
      const int ua = ks * 4 + lg;
      s16x8 a[4], xf[8];
      #pragma unroll
      for (int mi = 0; mi < 4; ++mi) {
        int r = wm*64 + mi*16 + lr;
        a[mi] = *(const s16x8*)&Ks[cur][r * 64 + (ua ^ (r & 7)) * 8];
      }
      #pragma unroll
      for (int nj = 0; nj < 8; ++nj) {
        int r = wn*128 + nj*16 + lr;
        xf[nj] = *(const s16x8*)&Xs[cur][r * 64 + (ua ^ (r & 7)) * 8];
      }
      #pragma unroll
      for (int mi = 0; mi < 4; ++mi)
        #pragma unroll
        for (int nj = 0; nj < 8; ++nj)
          acc[mi][nj] = __builtin_amdgcn_mfma_f32_16x16x32_bf16(
              a[mi], xf[nj], acc[mi][nj], 0, 0, 0);
    }
    __syncthreads();
  }

  if (PART) {
    short* P = (short*)(ws + WS_P) + ((size_t)((mat*2 + b)*64 + chunk)) * 65536;
    #pragma unroll
    for (int mi = 0; mi < 4; ++mi)
      #pragma unroll
      for (int nj = 0; nj < 8; ++nj) {
        int i = wm*64 + mi*16 + lg*4;
        int j = wn*128 + nj*16 + lr;
        #pragma unroll
        for (int ii = 0; ii < 4; ++ii)
          P[(size_t)(i + ii) * 256 + j] = f2bf(acc[mi][nj][ii]);
      }
  } else {
    float* M = (float*)(ws + (mat ? WS_M2 : WS_M1)) + (size_t)b * CC * CC;
    #pragma unroll
    for (int mi = 0; mi < 4; ++mi)
      #pragma unroll
      for (int nj = 0; nj < 8; ++nj) {
        int i = wm*64 + mi*16 + lg*4;
        int j = wn*128 + nj*16 + lr;
        #pragma unroll
        for (int ii = 0; ii < 4; ++ii)
          atomicAdd(&M[(size_t)(i + ii) * 256 + j], acc[mi][nj][ii]);
      }
  }
}

// ---------------- k25: reduce bf16 partials -> f32 m1/m2 ----------------------
__global__ __launch_bounds__(256) void k25_reduce(char* __restrict__ ws)
{
  int idx = blockIdx.x * 256 + threadIdx.x;
  int mb = idx >> 16;
  int ij = idx & 65535;
  const short* P = (const short*)(ws + WS_P) + ((size_t)mb * 64) * 65536 + ij;
  float s = 0.f;
  #pragma unroll 8
  for (int c = 0; c < 64; ++c)
    s += bf2f(P[(size_t)c * 65536]);
  float* dst = (float*)(ws + ((mb >> 1) ? WS_M2 : WS_M1)) + (size_t)(mb & 1) * 65536 + ij;
  *dst = s;
}

// ---------------- k3: affinity = sigmoid(m1 @ m2) -> bf16 ---------------------
__global__ __launch_bounds__(256) void k3_aff(char* __restrict__ ws)
{
  const int j = threadIdx.x;
  const int i = blockIdx.x & 255;
  const int b = blockIdx.x >> 8;
  const float* m1 = (const float*)(ws + WS_M1) + (size_t)b * CC * CC;
  const float* m2 = (const float*)(ws + WS_M2) + (size_t)b * CC * CC;
  float z = 0.f;
  #pragma unroll 8
  for (int k = 0; k < 256; ++k)
    z = fmaf(m1[i*256 + k], m2[k*256 + j], z);
  float a = 1.f / (1.f + expf(-z));
  ((short*)(ws + WS_AFF))[(size_t)b*CC*CC + i*256 + j] = f2bf(a);
}

// ---------------- k4: out = gamma * (affinity @ V) + x ------------------------
__global__ __launch_bounds__(512, 4) void k4_out(
    const float* __restrict__ x, const float* __restrict__ gamma_p,
    char* __restrict__ ws, float* __restrict__ out)
{
  __shared__ short affS[256][72];
  __shared__ short Vs[128][72];

  const int tid = threadIdx.x;
  const int n0 = blockIdx.x * 128;
  const int b  = blockIdx.y;
  const float gamma = gamma_p[0];
  const short* aff = (const short*)(ws + WS_AFF) + (size_t)b * CC * CC;
  const short* Vm  = (const short*)(ws + WS_V) + (size_t)b * NVOX * CC;

  const int lane = tid & 63, wid = tid >> 6;
  const int wi = wid >> 1, wn = wid & 1;
  const int lr = lane & 15, lg = lane >> 4;

  f32x4 acc[4][4];
  #pragma unroll
  for (int a = 0; a < 4; ++a)
    #pragma unroll
    for (int c = 0; c < 4; ++c) { f32x4 z = {0.f,0.f,0.f,0.f}; acc[a][c] = z; }

  for (int c0 = 0; c0 < 256; c0 += 64) {
    __syncthreads();
    #pragma unroll
    for (int it = 0; it < 4; ++it) {
      int idx = tid + 512 * it;
      int r = idx >> 3, c8 = (idx & 7) << 3;
      *(s16x8*)&affS[r][c8] = *(const s16x8*)&aff[(size_t)r * 256 + c0 + c8];
    }
    #pragma unroll
    for (int it = 0; it < 2; ++it) {
      int idx = tid + 512 * it;
      int t15 = idx & 15;
      int cc = idx >> 4, n8 = t15 << 3;
      s16x8 v = *(const s16x8*)&Vm[(size_t)(c0 + cc) * NVOX + n0 + n8];
      #pragma unroll
      for (int uu = 0; uu < 8; ++uu) {
        int u = (uu + t15) & 7;
        Vs[n8 + u][cc] = v[u];
      }
    }
    __syncthreads();
    #pragma unroll
    for (int ks = 0; ks < 2; ++ks) {
      s16x8 af[4], bv[4];
      #pragma unroll
      for (int mi = 0; mi < 4; ++mi)
        af[mi] = *(const s16x8*)&affS[wi*64 + mi*16 + lr][ks*32 + lg*8];
      #pragma unroll
      for (int nj = 0; nj < 4; ++nj)
        bv[nj] = *(const s16x8*)&Vs[wn*64 + nj*16 + lr][ks*32 + lg*8];
      #pragma unroll
      for (int mi = 0; mi < 4; ++mi)
        #pragma unroll
        for (int nj = 0; nj < 4; ++nj)
          acc[mi][nj] = __builtin_amdgcn_mfma_f32_16x16x32_bf16(
              bv[nj], af[mi], acc[mi][nj], 0, 0, 0);
    }
  }
  #pragma unroll
  for (int mi = 0; mi < 4; ++mi)
    #pragma unroll
    for (int nj = 0; nj < 4; ++nj) {
      int i = wi*64 + mi*16 + lr;
      int n = n0 + wn*64 + nj*16 + lg*4;
      size_t flat = (size_t)b * NVOX * CC + (size_t)i * NVOX + n;
      const float4 xv = *(const float4*)(x + flat);
      float4 o;
      o.x = gamma * acc[mi][nj][0] + xv.x;
      o.y = gamma * acc[mi][nj][1] + xv.y;
      o.z = gamma * acc[mi][nj][2] + xv.z;
      o.w = gamma * acc[mi][nj][3] + xv.w;
      *(float4*)(out + flat) = o;
    }
}

// ---------------- launcher ----------------------------------------------------
extern "C" void kernel_launch(void* const* d_in, const int* in_sizes, int n_in,
                              void* d_out, int out_size, void* d_ws, size_t ws_size,
                              hipStream_t stream)
{
  const float* x      = (const float*)d_in[0];
  const float* conv_w = (const float*)d_in[1];
  const float* conv_b = (const float*)d_in[2];
  const float* bn_s   = (const float*)d_in[3];
  const float* bn_o   = (const float*)d_in[4];
  const float* bn_m   = (const float*)d_in[5];
  const float* bn_v   = (const float*)d_in[6];
  const float* gamma  = (const float*)d_in[7];
  char*  ws  = (char*)d_ws;
  float* out = (float*)d_out;

  const bool part = ws_size >= WS_NEED_PART;

  k0_prep    <<<1024, 256, 0, stream>>>(conv_w, conv_b, bn_s, bn_o, bn_m, bn_v, ws);
  if (part) {
    k0b_convert<<<1024, 256, 0, stream>>>(x, ws);
    k1b_gemm   <<<4096, 256, 0, stream>>>(ws);
    k2_m1m2<1> <<<dim3(64, 2, 2), 512, 0, stream>>>(ws);
    k25_reduce <<<1024, 256, 0, stream>>>(ws);
  } else {
    k1_branches<<<1024, 256, 0, stream>>>(x, ws);
    k2_m1m2<0> <<<dim3(64, 2, 2), 512, 0, stream>>>(ws);
  }
  k3_aff     <<<512, 256, 0, stream>>>(ws);
  k4_out     <<<dim3(256, 2), 512, 0, stream>>>(x, gamma, ws, out);
}

// Round 13
// 207.198 us; speedup vs baseline: 1.0769x; 1.0769x over previous
//
#include <hip/hip_runtime.h>
#include <math.h>

typedef __attribute__((ext_vector_type(4))) float  f32x4;
typedef __attribute__((ext_vector_type(8))) short  s16x8;
typedef __attribute__((ext_vector_type(4))) short  s16x4;

#define BN_EPS 1e-3f
#define AS1 const __attribute__((address_space(1))) void*
#define AS3 __attribute__((address_space(3))) void*

static constexpr int    CC    = 256;
static constexpr int    NVOX  = 32768;
static constexpr int    BATCH = 2;
static constexpr int    MTOT  = BATCH * NVOX;              // 65536 rows
static constexpr size_t ELEM_BR = (size_t)MTOT * CC;       // 16,777,216 per branch
static constexpr size_t SZ_BR   = ELEM_BR * 2;             // bf16 bytes
// workspace layout
static constexpr size_t WS_Q   = 0;
static constexpr size_t WS_K   = WS_Q  + SZ_BR;
static constexpr size_t WS_J   = WS_K  + SZ_BR;
static constexpr size_t WS_V   = WS_J  + SZ_BR;
static constexpr size_t WS_M1  = WS_V  + SZ_BR;                       // f32 [2][256][256]
static constexpr size_t WS_M2  = WS_M1 + (size_t)BATCH*CC*CC*4;
static constexpr size_t WS_AFF = WS_M2 + (size_t)BATCH*CC*CC*4;       // bf16 [2][256][256]
static constexpr size_t WS_WT  = WS_AFF + (size_t)BATCH*CC*CC*2;      // bf16 Wt[4][cout][cin]
static constexpr size_t WS_AB  = WS_WT + (size_t)4*CC*CC*2;           // f32 alpha[1024], beta[1024]
static constexpr size_t WS_P   = WS_AB + 2048*4;                      // bf16 partials [4][64][65536]
static constexpr size_t WS_NEED_PART = WS_P + (size_t)4*64*65536*2;   // ~162 MiB

__device__ __forceinline__ short f2bf(float f) {
  union { float f; unsigned u; } v; v.f = f;
  unsigned u = v.u + 0x7FFFu + ((v.u >> 16) & 1u);   // RNE
  return (short)(u >> 16);
}
__device__ __forceinline__ float bf2f(short s) {
  union { unsigned u; float f; } v; v.u = ((unsigned)(unsigned short)s) << 16;
  return v.f;
}
__device__ __forceinline__ unsigned long long packBN(f32x4 a, f32x4 al, f32x4 be) {
  union { s16x4 v; unsigned long long u; } c;
  #pragma unroll
  for (int ii = 0; ii < 4; ++ii) {
    float yv = al[ii] * a[ii] + be[ii];
    c.v[ii] = f2bf(yv > 0.f ? yv : 0.f);
  }
  return c.u;
}

// ---------------- k0: prep — weights bf16, fold BN, zero m1/m2 ----------------
__global__ __launch_bounds__(256) void k0_prep(
    const float* __restrict__ conv_w, const float* __restrict__ conv_b,
    const float* __restrict__ bn_s, const float* __restrict__ bn_o,
    const float* __restrict__ bn_m, const float* __restrict__ bn_v,
    char* __restrict__ ws)
{
  int t = blockIdx.x * 256 + threadIdx.x;              // 0..262143
  ((float*)(ws + WS_M1))[t] = 0.f;
  int f = t >> 16, rem = t & 65535;
  int cin = rem >> 8, cout = rem & 255;
  ((short*)(ws + WS_WT))[f*65536 + cout*256 + cin] = f2bf(conv_w[t]);
  if (t < 1024) {
    float alpha = bn_s[t] * rsqrtf(bn_v[t] + BN_EPS);
    float beta  = alpha * (conv_b[t] - bn_m[t]) + bn_o[t];
    float* ab = (float*)(ws + WS_AB);
    ab[t] = alpha; ab[1024 + t] = beta;
  }
}

// ---------------- k1: 4 fused conv+BN+ReLU branches (r8 structure) ------------
// ONLY change vs round 8: Rs repack replaced by shfl-pack direct stores
// (proven conflict-free in k1b, correctness-validated r11/r12). LDS 64KB.
__global__ __launch_bounds__(256, 2) void k1_branches(
    const float* __restrict__ x, char* __restrict__ ws)
{
  __shared__ short As[64 * 256];
  __shared__ short Bs[64 * 256];

  const int tid = threadIdx.x;
  const int m0  = blockIdx.x * 64;
  const int lane = tid & 63, wid = tid >> 6;
  const int wm = wid >> 1, wn = wid & 1;        // 2x2 waves over 64x64 tile
  const int lr = lane & 15, lg = lane >> 4;

  const short* Wt = (const short*)(ws + WS_WT);
  const float* ab = (const float*)(ws + WS_AB);

  // ---- stage A: 64x256 f32 -> bf16, swizzled
  #pragma unroll
  for (int it = 0; it < 16; ++it) {
    int idx = tid + 256 * it;
    int r = idx >> 6, c4 = (idx & 63) << 2;
    const float4 v = *(const float4*)(x + (size_t)(m0 + r) * 256 + c4);
    s16x4 s; s[0]=f2bf(v.x); s[1]=f2bf(v.y); s[2]=f2bf(v.z); s[3]=f2bf(v.w);
    int u = c4 >> 3;
    int swz = ((u ^ ((r & 7) << 2)) << 3) | (c4 & 7);
    *(s16x4*)&As[r * 256 + swz] = s;
  }

  // ---- stage Bs for nt=0
  {
    #pragma unroll
    for (int i = 0; i < 8; ++i) {
      int slot = i * 256 + tid;
      int cout = slot >> 5, u = slot & 31;
      int usrc = u ^ ((cout & 7) << 2);
      __builtin_amdgcn_global_load_lds(
          (AS1)(Wt + cout * 256 + usrc * 8),
          (AS3)(Bs + (size_t)(i * 256 + wid * 64) * 8), 16, 0, 0);
    }
  }
  __syncthreads();

  for (int nt = 0; nt < 16; ++nt) {
    const int f  = nt >> 2;
    const int c0 = (nt & 3) * 64;

    f32x4 acc[2][2];
    #pragma unroll
    for (int a = 0; a < 2; ++a)
      #pragma unroll
      for (int b = 0; b < 2; ++b) { f32x4 z = {0.f,0.f,0.f,0.f}; acc[a][b] = z; }

    #pragma unroll
    for (int k0 = 0; k0 < 8; ++k0) {
      const int ua = k0 * 4 + lg;
      s16x8 af[2], bf[2];
      #pragma unroll
      for (int mi = 0; mi < 2; ++mi) {
        int r = wm*32 + mi*16 + lr;
        af[mi] = *(const s16x8*)&As[r * 256 + (ua ^ ((r & 7) << 2)) * 8];
      }
      #pragma unroll
      for (int nj = 0; nj < 2; ++nj) {
        int c = wn*32 + nj*16 + lr;
        bf[nj] = *(const s16x8*)&Bs[c * 256 + (ua ^ ((c & 7) << 2)) * 8];
      }
      #pragma unroll
      for (int mi = 0; mi < 2; ++mi)
        #pragma unroll
        for (int nj = 0; nj < 2; ++nj)
          acc[mi][nj] = __builtin_amdgcn_mfma_f32_16x16x32_bf16(
              bf[nj], af[mi], acc[mi][nj], 0, 0, 0);   // D = W·A^T
    }

    __syncthreads();                           // barrier_A: all Bs reads done

    // ---- issue next nt's B stage; latency hides under store epilogue
    if (nt < 15) {
      const int fn  = (nt + 1) >> 2;
      const int c0n = ((nt + 1) & 3) * 64;
      const short* Wfp = Wt + fn * 65536 + c0n * 256;
      #pragma unroll
      for (int i = 0; i < 8; ++i) {
        int slot = i * 256 + tid;
        int cout = slot >> 5, u = slot & 31;
        int usrc = u ^ ((cout & 7) << 2);
        __builtin_amdgcn_global_load_lds(
            (AS1)(Wfp + cout * 256 + usrc * 8),
            (AS3)(Bs + (size_t)(i * 256 + wid * 64) * 8), 16, 0, 0);
      }
    }

    // ---- epilogue: BN+ReLU -> shfl-pack -> direct 16B stores (no Rs LDS)
    // mapping: row = m0+wm*32+mi*16+lr; couts [c0+wn*32, +32) per wave
    short* Yf = (short*)(ws + (size_t)f * SZ_BR);
    const int cwb = c0 + wn * 32;
    {
      const int ca = cwb + lg * 4;
      const f32x4 al0 = *(const f32x4*)&ab[f*256 + ca];
      const f32x4 be0 = *(const f32x4*)&ab[1024 + f*256 + ca];
      const f32x4 al1 = *(const f32x4*)&ab[f*256 + ca + 16];
      const f32x4 be1 = *(const f32x4*)&ab[1024 + f*256 + ca + 16];
      const int cout_s = cwb + (lg & 1) * 16 + (lg >> 1) * 8;
      #pragma unroll
      for (int mi = 0; mi < 2; ++mi) {
        unsigned long long p0 = packBN(acc[mi][0], al0, be0);
        unsigned long long p1 = packBN(acc[mi][1], al1, be1);
        unsigned long long q0 = __shfl_xor(p0, 16, 64);
        unsigned long long q1 = __shfl_xor(p1, 16, 64);
        ulonglong2 ch0, ch1;
        if (lg & 1) { ch0.x = q0; ch0.y = p0; ch1.x = q1; ch1.y = p1; }
        else        { ch0.x = p0; ch0.y = q0; ch1.x = p1; ch1.y = q1; }
        ulonglong2 sel = (lg & 1) ? ch1 : ch0;
        const size_t row = (size_t)(m0 + wm*32 + mi*16 + lr);
        *(ulonglong2*)&Yf[row * 256 + cout_s] = sel;
      }
    }

    __syncthreads();                           // barrier_B: stage drained
  }
}

// ---------------- k2: m1 = K*Q^T, m2 = K*J^T ---------------------------------
template<int PART>
__global__ __launch_bounds__(512, 2) void k2_m1m2(char* __restrict__ ws)
{
  __shared__ short Ks[2][16384];
  __shared__ short Xs[2][16384];

  const int tid = threadIdx.x;
  const int chunk = blockIdx.x;
  const int mat = blockIdx.y;
  const int b   = blockIdx.z;
  const size_t boff = (size_t)b * NVOX * CC;
  const short* Km = (const short*)(ws + WS_K) + boff;
  const short* Xm = (const short*)(ws + (mat ? WS_J : WS_Q)) + boff;

  const int lane = tid & 63, wid = tid >> 6;
  const int wm = wid >> 1, wn = wid & 1;
  const int lr = lane & 15, lg = lane >> 4;

  f32x4 acc[4][8];
  #pragma unroll
  for (int a = 0; a < 4; ++a)
    #pragma unroll
    for (int c = 0; c < 8; ++c) { f32x4 z = {0.f,0.f,0.f,0.f}; acc[a][c] = z; }

  {
    const int n0 = chunk * 512;
    #pragma unroll
    for (int i = 0; i < 4; ++i) {
      int slot = i * 512 + tid;
      int r = slot >> 3, u = slot & 7;
      int usrc = u ^ (r & 7);
      const size_t so = (size_t)r * NVOX + n0 + usrc * 8;
      __builtin_amdgcn_global_load_lds((AS1)(Km + so),
          (AS3)(Ks[0] + (size_t)(i * 512 + wid * 64) * 8), 16, 0, 0);
      __builtin_amdgcn_global_load_lds((AS1)(Xm + so),
          (AS3)(Xs[0] + (size_t)(i * 512 + wid * 64) * 8), 16, 0, 0);
    }
  }
  __syncthreads();

  for (int t = 0; t < 8; ++t) {
    const int cur = t & 1;
    if (t < 7) {
      const int n0n = chunk * 512 + (t + 1) * 64;
      const int nxt = cur ^ 1;
      #pragma unroll
      for (int i = 0; i < 4; ++i) {
        int slot = i * 512 + tid;
        int r = slot >> 3, u = slot & 7;
        int usrc = u ^ (r & 7);
        const size_t so = (size_t)r * NVOX + n0n + usrc * 8;
        __builtin_amdgcn_global_load_lds((AS1)(Km + so),
            (AS3)(Ks[nxt] + (size_t)(i * 512 + wid * 64) * 8), 16, 0, 0);
        __builtin_amdgcn_global_load_lds((AS1)(Xm + so),
            (AS3)(Xs[nxt] + (size_t)(i * 512 + wid * 64) * 8), 16, 0, 0);
      }
    }
    #pragma unroll
    for (int ks = 0; ks < 2; ++ks) {
      const int ua = ks * 4 + lg;
      s16x8 a[4], xf[8];
      #pragma unroll
      for (int mi = 0; mi < 4; ++mi) {
        int r = wm*64 + mi*16 + lr;
        a[mi] = *(const s16x8*)&Ks[cur][r * 64 + (ua ^ (r & 7)) * 8];
      }
      #pragma unroll
      for (int nj = 0; nj < 8; ++nj) {
        int r = wn*128 + nj*16 + lr;
        xf[nj] = *(const s16x8*)&Xs[cur][r * 64 + (ua ^ (r & 7)) * 8];
      }
      #pragma unroll
      for (int mi = 0; mi < 4; ++mi)
        #pragma unroll
        for (int nj = 0; nj < 8; ++nj)
          acc[mi][nj] = __builtin_amdgcn_mfma_f32_16x16x32_bf16(
              a[mi], xf[nj], acc[mi][nj], 0, 0, 0);
    }
    __syncthreads();
  }

  if (PART) {
    short* P = (short*)(ws + WS_P) + ((size_t)((mat*2 + b)*64 + chunk)) * 65536;
    #pragma unroll
    for (int mi = 0; mi < 4; ++mi)
      #pragma unroll
      for (int nj = 0; nj < 8; ++nj) {
        int i = wm*64 + mi*16 + lg*4;
        int j = wn*128 + nj*16 + lr;
        #pragma unroll
        for (int ii = 0; ii < 4; ++ii)
          P[(size_t)(i + ii) * 256 + j] = f2bf(acc[mi][nj][ii]);
      }
  } else {
    float* M = (float*)(ws + (mat ? WS_M2 : WS_M1)) + (size_t)b * CC * CC;
    #pragma unroll
    for (int mi = 0; mi < 4; ++mi)
      #pragma unroll
      for (int nj = 0; nj < 8; ++nj) {
        int i = wm*64 + mi*16 + lg*4;
        int j = wn*128 + nj*16 + lr;
        #pragma unroll
        for (int ii = 0; ii < 4; ++ii)
          atomicAdd(&M[(size_t)(i + ii) * 256 + j], acc[mi][nj][ii]);
      }
  }
}

// ---------------- k25: reduce bf16 partials -> f32 m1/m2 ----------------------
__global__ __launch_bounds__(256) void k25_reduce(char* __restrict__ ws)
{
  int idx = blockIdx.x * 256 + threadIdx.x;
  int mb = idx >> 16;
  int ij = idx & 65535;
  const short* P = (const short*)(ws + WS_P) + ((size_t)mb * 64) * 65536 + ij;
  float s = 0.f;
  #pragma unroll 8
  for (int c = 0; c < 64; ++c)
    s += bf2f(P[(size_t)c * 65536]);
  float* dst = (float*)(ws + ((mb >> 1) ? WS_M2 : WS_M1)) + (size_t)(mb & 1) * 65536 + ij;
  *dst = s;
}

// ---------------- k3: affinity = sigmoid(m1 @ m2) -> bf16 ---------------------
__global__ __launch_bounds__(256) void k3_aff(char* __restrict__ ws)
{
  const int j = threadIdx.x;
  const int i = blockIdx.x & 255;
  const int b = blockIdx.x >> 8;
  const float* m1 = (const float*)(ws + WS_M1) + (size_t)b * CC * CC;
  const float* m2 = (const float*)(ws + WS_M2) + (size_t)b * CC * CC;
  float z = 0.f;
  #pragma unroll 8
  for (int k = 0; k < 256; ++k)
    z = fmaf(m1[i*256 + k], m2[k*256 + j], z);
  float a = 1.f / (1.f + expf(-z));
  ((short*)(ws + WS_AFF))[(size_t)b*CC*CC + i*256 + j] = f2bf(a);
}

// ---------------- k4: out = gamma * (affinity @ V) + x ------------------------
__global__ __launch_bounds__(512, 4) void k4_out(
    const float* __restrict__ x, const float* __restrict__ gamma_p,
    char* __restrict__ ws, float* __restrict__ out)
{
  __shared__ short affS[256][72];
  __shared__ short Vs[128][72];

  const int tid = threadIdx.x;
  const int n0 = blockIdx.x * 128;
  const int b  = blockIdx.y;
  const float gamma = gamma_p[0];
  const short* aff = (const short*)(ws + WS_AFF) + (size_t)b * CC * CC;
  const short* Vm  = (const short*)(ws + WS_V) + (size_t)b * NVOX * CC;

  const int lane = tid & 63, wid = tid >> 6;
  const int wi = wid >> 1, wn = wid & 1;
  const int lr = lane & 15, lg = lane >> 4;

  f32x4 acc[4][4];
  #pragma unroll
  for (int a = 0; a < 4; ++a)
    #pragma unroll
    for (int c = 0; c < 4; ++c) { f32x4 z = {0.f,0.f,0.f,0.f}; acc[a][c] = z; }

  for (int c0 = 0; c0 < 256; c0 += 64) {
    __syncthreads();
    #pragma unroll
    for (int it = 0; it < 4; ++it) {
      int idx = tid + 512 * it;
      int r = idx >> 3, c8 = (idx & 7) << 3;
      *(s16x8*)&affS[r][c8] = *(const s16x8*)&aff[(size_t)r * 256 + c0 + c8];
    }
    #pragma unroll
    for (int it = 0; it < 2; ++it) {
      int idx = tid + 512 * it;
      int t15 = idx & 15;
      int cc = idx >> 4, n8 = t15 << 3;
      s16x8 v = *(const s16x8*)&Vm[(size_t)(c0 + cc) * NVOX + n0 + n8];
      #pragma unroll
      for (int uu = 0; uu < 8; ++uu) {
        int u = (uu + t15) & 7;
        Vs[n8 + u][cc] = v[u];
      }
    }
    __syncthreads();
    #pragma unroll
    for (int ks = 0; ks < 2; ++ks) {
      s16x8 af[4], bv[4];
      #pragma unroll
      for (int mi = 0; mi < 4; ++mi)
        af[mi] = *(const s16x8*)&affS[wi*64 + mi*16 + lr][ks*32 + lg*8];
      #pragma unroll
      for (int nj = 0; nj < 4; ++nj)
        bv[nj] = *(const s16x8*)&Vs[wn*64 + nj*16 + lr][ks*32 + lg*8];
      #pragma unroll
      for (int mi = 0; mi < 4; ++mi)
        #pragma unroll
        for (int nj = 0; nj < 4; ++nj)
          acc[mi][nj] = __builtin_amdgcn_mfma_f32_16x16x32_bf16(
              bv[nj], af[mi], acc[mi][nj], 0, 0, 0);
    }
  }
  #pragma unroll
  for (int mi = 0; mi < 4; ++mi)
    #pragma unroll
    for (int nj = 0; nj < 4; ++nj) {
      int i = wi*64 + mi*16 + lr;
      int n = n0 + wn*64 + nj*16 + lg*4;
      size_t flat = (size_t)b * NVOX * CC + (size_t)i * NVOX + n;
      const float4 xv = *(const float4*)(x + flat);
      float4 o;
      o.x = gamma * acc[mi][nj][0] + xv.x;
      o.y = gamma * acc[mi][nj][1] + xv.y;
      o.z = gamma * acc[mi][nj][2] + xv.z;
      o.w = gamma * acc[mi][nj][3] + xv.w;
      *(float4*)(out + flat) = o;
    }
}

// ---------------- launcher ----------------------------------------------------
extern "C" void kernel_launch(void* const* d_in, const int* in_sizes, int n_in,
                              void* d_out, int out_size, void* d_ws, size_t ws_size,
                              hipStream_t stream)
{
  const float* x      = (const float*)d_in[0];
  const float* conv_w = (const float*)d_in[1];
  const float* conv_b = (const float*)d_in[2];
  const float* bn_s   = (const float*)d_in[3];
  const float* bn_o   = (const float*)d_in[4];
  const float* bn_m   = (const float*)d_in[5];
  const float* bn_v   = (const float*)d_in[6];
  const float* gamma  = (const float*)d_in[7];
  char*  ws  = (char*)d_ws;
  float* out = (float*)d_out;

  const bool part = ws_size >= WS_NEED_PART;

  k0_prep    <<<1024, 256, 0, stream>>>(conv_w, conv_b, bn_s, bn_o, bn_m, bn_v, ws);
  k1_branches<<<1024, 256, 0, stream>>>(x, ws);
  if (part) {
    k2_m1m2<1><<<dim3(64, 2, 2), 512, 0, stream>>>(ws);
    k25_reduce<<<1024, 256, 0, stream>>>(ws);
  } else {
    k2_m1m2<0><<<dim3(64, 2, 2), 512, 0, stream>>>(ws);
  }
  k3_aff     <<<512, 256, 0, stream>>>(ws);
  k4_out     <<<dim3(256, 2), 512, 0, stream>>>(x, gamma, ws, out);
}

// Round 14
// 166.545 us; speedup vs baseline: 1.3397x; 1.2441x over previous
//
#include <hip/hip_runtime.h>
#include <math.h>

typedef __attribute__((ext_vector_type(4))) float  f32x4;
typedef __attribute__((ext_vector_type(8))) short  s16x8;
typedef __attribute__((ext_vector_type(4))) short  s16x4;

#define BN_EPS 1e-3f

static constexpr int    CC    = 256;
static constexpr int    NVOX  = 32768;
static constexpr int    BATCH = 2;
static constexpr int    MTOT  = BATCH * NVOX;              // 65536 rows
static constexpr size_t ELEM_BR = (size_t)MTOT * CC;       // 16,777,216 per branch
static constexpr size_t SZ_BR   = ELEM_BR * 2;             // bf16 bytes
// workspace layout
static constexpr size_t WS_Q   = 0;
static constexpr size_t WS_K   = WS_Q  + SZ_BR;
static constexpr size_t WS_J   = WS_K  + SZ_BR;
static constexpr size_t WS_V   = WS_J  + SZ_BR;
static constexpr size_t WS_M1  = WS_V  + SZ_BR;                       // f32 [2][256][256]
static constexpr size_t WS_M2  = WS_M1 + (size_t)BATCH*CC*CC*4;
static constexpr size_t WS_AFF = WS_M2 + (size_t)BATCH*CC*CC*4;       // bf16 [2][256][256]
static constexpr size_t WS_WT  = WS_AFF + (size_t)BATCH*CC*CC*2;      // bf16 Wt[4][cout][cin]
static constexpr size_t WS_AB  = WS_WT + (size_t)4*CC*CC*2;           // f32 alpha[1024], beta[1024]
static constexpr size_t WS_P   = WS_AB + 2048*4;                      // bf16 partials [4][64][65536]
static constexpr size_t WS_NEED_PART = WS_P + (size_t)4*64*65536*2;   // ~162 MiB

__device__ __forceinline__ short f2bf(float f) {
  union { float f; unsigned u; } v; v.f = f;
  unsigned u = v.u + 0x7FFFu + ((v.u >> 16) & 1u);   // RNE
  return (short)(u >> 16);
}
__device__ __forceinline__ float bf2f(short s) {
  union { unsigned u; float f; } v; v.u = ((unsigned)(unsigned short)s) << 16;
  return v.f;
}

// ---------------- k0: prep — transpose weights to bf16, fold BN, zero m1/m2 ----
__global__ __launch_bounds__(256) void k0_prep(
    const float* __restrict__ conv_w, const float* __restrict__ conv_b,
    const float* __restrict__ bn_s, const float* __restrict__ bn_o,
    const float* __restrict__ bn_m, const float* __restrict__ bn_v,
    char* __restrict__ ws)
{
  int t = blockIdx.x * 256 + threadIdx.x;              // 0..262143
  ((float*)(ws + WS_M1))[t] = 0.f;                     // zero m1+m2 (2*2*65536 f32)
  int f = t >> 16, rem = t & 65535;
  int cin = rem >> 8, cout = rem & 255;
  ((short*)(ws + WS_WT))[f*65536 + cout*256 + cin] = f2bf(conv_w[t]);
  if (t < 1024) {
    float alpha = bn_s[t] * rsqrtf(bn_v[t] + BN_EPS);
    float beta  = alpha * (conv_b[t] - bn_m[t]) + bn_o[t];
    float* ab = (float*)(ws + WS_AB);
    ab[t] = alpha; ab[1024 + t] = beta;
  }
}

// ---------------- k1: 4 fused conv+BN+ReLU branches (round-4 structure, 80us) --
__global__ __launch_bounds__(256, 2) void k1_branches(
    const float* __restrict__ x, char* __restrict__ ws)
{
  __shared__ short As[64 * 256];
  __shared__ short Bs[64 * 256];
  __shared__ short Rs[64][72];     // repack (row stride 144B = 9 x 16B)

  const int tid = threadIdx.x;
  const int m0  = blockIdx.x * 64;
  const int lane = tid & 63, wid = tid >> 6;
  const int wm = wid >> 1, wn = wid & 1;        // 2x2 waves over 64x64 tile
  const int lr = lane & 15, lg = lane >> 4;

  const short* Wt = (const short*)(ws + WS_WT);
  const float* ab = (const float*)(ws + WS_AB);

  #pragma unroll
  for (int it = 0; it < 16; ++it) {
    int idx = tid + 256 * it;
    int r = idx >> 6, c4 = (idx & 63) << 2;
    const float4 v = *(const float4*)(x + (size_t)(m0 + r) * 256 + c4);
    s16x4 s; s[0]=f2bf(v.x); s[1]=f2bf(v.y); s[2]=f2bf(v.z); s[3]=f2bf(v.w);
    int u = c4 >> 3;
    int swz = ((u ^ ((r & 7) << 2)) << 3) | (c4 & 7);
    *(s16x4*)&As[r * 256 + swz] = s;
  }

  {
    const short* Wf = Wt;
    #pragma unroll
    for (int i = 0; i < 8; ++i) {
      int slot = i * 256 + tid;
      int cout = slot >> 5, u = slot & 31;
      int usrc = u ^ ((cout & 7) << 2);
      const short* src = Wf + cout * 256 + usrc * 8;
      short* dst = Bs + (size_t)(i * 256 + wid * 64) * 8;
      __builtin_amdgcn_global_load_lds(
          (const __attribute__((address_space(1))) void*)src,
          (__attribute__((address_space(3))) void*)dst, 16, 0, 0);
    }
  }

  __syncthreads();

  for (int nt = 0; nt < 16; ++nt) {
    const int f  = nt >> 2;
    const int c0 = (nt & 3) * 64;

    f32x4 acc[2][2];
    #pragma unroll
    for (int a = 0; a < 2; ++a)
      #pragma unroll
      for (int b = 0; b < 2; ++b) { f32x4 z = {0.f,0.f,0.f,0.f}; acc[a][b] = z; }

    #pragma unroll
    for (int k0 = 0; k0 < 8; ++k0) {
      const int ua = k0 * 4 + lg;
      s16x8 af[2], bf[2];
      #pragma unroll
      for (int mi = 0; mi < 2; ++mi) {
        int r = wm*32 + mi*16 + lr;
        int uu = ua ^ ((r & 7) << 2);
        af[mi] = *(const s16x8*)&As[r * 256 + uu * 8];
      }
      #pragma unroll
      for (int nj = 0; nj < 2; ++nj) {
        int c = wn*32 + nj*16 + lr;
        int uu = ua ^ ((c & 7) << 2);
        bf[nj] = *(const s16x8*)&Bs[c * 256 + uu * 8];
      }
      #pragma unroll
      for (int mi = 0; mi < 2; ++mi)
        #pragma unroll
        for (int nj = 0; nj < 2; ++nj)
          acc[mi][nj] = __builtin_amdgcn_mfma_f32_16x16x32_bf16(
              bf[nj], af[mi], acc[mi][nj], 0, 0, 0);   // D = W·A^T
    }

    __syncthreads();                           // barrier_A

    if (nt < 15) {
      const int fn  = (nt + 1) >> 2;
      const int c0n = ((nt + 1) & 3) * 64;
      const short* Wf = Wt + fn * 65536 + c0n * 256;
      #pragma unroll
      for (int i = 0; i < 8; ++i) {
        int slot = i * 256 + tid;
        int cout = slot >> 5, u = slot & 31;
        int usrc = u ^ ((cout & 7) << 2);
        const short* src = Wf + cout * 256 + usrc * 8;
        short* dst = Bs + (size_t)(i * 256 + wid * 64) * 8;
        __builtin_amdgcn_global_load_lds(
            (const __attribute__((address_space(1))) void*)src,
            (__attribute__((address_space(3))) void*)dst, 16, 0, 0);
      }
    }

    #pragma unroll
    for (int nj = 0; nj < 2; ++nj) {
      int c4b = c0 + wn*32 + nj*16 + lg*4;
      const f32x4 al = *(const f32x4*)&ab[f*256 + c4b];
      const f32x4 be = *(const f32x4*)&ab[1024 + f*256 + c4b];
      #pragma unroll
      for (int mi = 0; mi < 2; ++mi) {
        s16x4 s;
        #pragma unroll
        for (int ii = 0; ii < 4; ++ii) {
          float yv = al[ii] * acc[mi][nj][ii] + be[ii];
          yv = yv > 0.f ? yv : 0.f;
          s[ii] = f2bf(yv);
        }
        *(s16x4*)&Rs[wm*32 + mi*16 + lr][wn*32 + nj*16 + lg*4] = s;
      }
    }

    __syncthreads();                           // barrier_B

    short* Yf = (short*)(ws + (size_t)f * SZ_BR);
    #pragma unroll
    for (int it = 0; it < 2; ++it) {
      int idx = tid + 256 * it;
      int r = idx >> 3, c8 = (idx & 7) << 3;
      *(s16x8*)&Yf[(size_t)(m0 + r) * 256 + c0 + c8] = *(const s16x8*)&Rs[r][c8];
    }
  }
}

// ---------------- k2: m1 = K*Q^T, m2 = K*J^T ---------------------------------
// 256 blocks (64 chunks x 2 matrices x 2 batches), 512 threads, full 256x256
// partial per block (acc 128 f32/thread). Double-buffered global_load_lds
// staging (K + Q-or-J, one barrier/tile). PART=1: bf16 partial -> ws (no
// atomics, k25 reduces). PART=0: f32 atomicAdd fallback.
template<int PART>
__global__ __launch_bounds__(512, 2) void k2_m1m2(char* __restrict__ ws)
{
  __shared__ short Ks[2][16384];   // [buf][256 rows x 64 n] 32KB each
  __shared__ short Xs[2][16384];

  const int tid = threadIdx.x;               // 0..511
  const int chunk = blockIdx.x;              // 64 chunks x 512 voxels
  const int mat = blockIdx.y;                // 0: m1 (X=Q), 1: m2 (X=J)
  const int b   = blockIdx.z;
  const size_t boff = (size_t)b * NVOX * CC;
  const short* Km = (const short*)(ws + WS_K) + boff;
  const short* Xm = (const short*)(ws + (mat ? WS_J : WS_Q)) + boff;

  const int lane = tid & 63, wid = tid >> 6;
  const int wm = wid >> 1, wn = wid & 1;     // 4 m-tiles(64 rows) x 2 n-tiles(128 cols)
  const int lr = lane & 15, lg = lane >> 4;

  f32x4 acc[4][8];
  #pragma unroll
  for (int a = 0; a < 4; ++a)
    #pragma unroll
    for (int c = 0; c < 8; ++c) { f32x4 z = {0.f,0.f,0.f,0.f}; acc[a][c] = z; }

  // stage tile 0 into buf 0
  {
    const int n0 = chunk * 512;
    #pragma unroll
    for (int i = 0; i < 4; ++i) {
      int slot = i * 512 + tid;              // 2048 16B-units per matrix tile
      int r = slot >> 3, u = slot & 7;
      int usrc = u ^ (r & 7);
      const size_t so = (size_t)r * NVOX + n0 + usrc * 8;
      short* dK = Ks[0] + (size_t)(i * 512 + wid * 64) * 8;
      short* dX = Xs[0] + (size_t)(i * 512 + wid * 64) * 8;
      __builtin_amdgcn_global_load_lds(
          (const __attribute__((address_space(1))) void*)(Km + so),
          (__attribute__((address_space(3))) void*)dK, 16, 0, 0);
      __builtin_amdgcn_global_load_lds(
          (const __attribute__((address_space(1))) void*)(Xm + so),
          (__attribute__((address_space(3))) void*)dX, 16, 0, 0);
    }
  }
  __syncthreads();

  for (int t = 0; t < 8; ++t) {
    const int cur = t & 1;
    // ---- issue stage(t+1) into other buffer; drained by end-of-iter barrier
    if (t < 7) {
      const int n0n = chunk * 512 + (t + 1) * 64;
      const int nxt = cur ^ 1;
      #pragma unroll
      for (int i = 0; i < 4; ++i) {
        int slot = i * 512 + tid;
        int r = slot >> 3, u = slot & 7;
        int usrc = u ^ (r & 7);
        const size_t so = (size_t)r * NVOX + n0n + usrc * 8;
        short* dK = Ks[nxt] + (size_t)(i * 512 + wid * 64) * 8;
        short* dX = Xs[nxt] + (size_t)(i * 512 + wid * 64) * 8;
        __builtin_amdgcn_global_load_lds(
            (const __attribute__((address_space(1))) void*)(Km + so),
            (__attribute__((address_space(3))) void*)dK, 16, 0, 0);
        __builtin_amdgcn_global_load_lds(
            (const __attribute__((address_space(1))) void*)(Xm + so),
            (__attribute__((address_space(3))) void*)dX, 16, 0, 0);
      }
    }
    // ---- compute tile t: 64 MFMA + 24 ds_read_b128 per thread
    #pragma unroll
    for (int ks = 0; ks < 2; ++ks) {
      const int ua = ks * 4 + lg;
      s16x8 a[4], xf[8];
      #pragma unroll
      for (int mi = 0; mi < 4; ++mi) {
        int r = wm*64 + mi*16 + lr;
        a[mi] = *(const s16x8*)&Ks[cur][r * 64 + (ua ^ (r & 7)) * 8];
      }
      #pragma unroll
      for (int nj = 0; nj < 8; ++nj) {
        int r = wn*128 + nj*16 + lr;
        xf[nj] = *(const s16x8*)&Xs[cur][r * 64 + (ua ^ (r & 7)) * 8];
      }
      #pragma unroll
      for (int mi = 0; mi < 4; ++mi)
        #pragma unroll
        for (int nj = 0; nj < 8; ++nj)
          acc[mi][nj] = __builtin_amdgcn_mfma_f32_16x16x32_bf16(
              a[mi], xf[nj], acc[mi][nj], 0, 0, 0);  // i rows from K, j cols from X
    }
    __syncthreads();
  }

  // ---- epilogue
  if (PART) {
    short* P = (short*)(ws + WS_P) + ((size_t)((mat*2 + b)*64 + chunk)) * 65536;
    #pragma unroll
    for (int mi = 0; mi < 4; ++mi)
      #pragma unroll
      for (int nj = 0; nj < 8; ++nj) {
        int i = wm*64 + mi*16 + lg*4;
        int j = wn*128 + nj*16 + lr;
        #pragma unroll
        for (int ii = 0; ii < 4; ++ii)
          P[(size_t)(i + ii) * 256 + j] = f2bf(acc[mi][nj][ii]);
      }
  } else {
    float* M = (float*)(ws + (mat ? WS_M2 : WS_M1)) + (size_t)b * CC * CC;
    #pragma unroll
    for (int mi = 0; mi < 4; ++mi)
      #pragma unroll
      for (int nj = 0; nj < 8; ++nj) {
        int i = wm*64 + mi*16 + lg*4;
        int j = wn*128 + nj*16 + lr;
        #pragma unroll
        for (int ii = 0; ii < 4; ++ii)
          atomicAdd(&M[(size_t)(i + ii) * 256 + j], acc[mi][nj][ii]);
      }
  }
}

// ---------------- k25: reduce bf16 partials -> f32 m1/m2 ----------------------
__global__ __launch_bounds__(256) void k25_reduce(char* __restrict__ ws)
{
  int idx = blockIdx.x * 256 + threadIdx.x;   // 0..262143
  int mb = idx >> 16;                         // mat*2 + batch
  int ij = idx & 65535;
  const short* P = (const short*)(ws + WS_P) + ((size_t)mb * 64) * 65536 + ij;
  float s = 0.f;
  #pragma unroll 8
  for (int c = 0; c < 64; ++c)
    s += bf2f(P[(size_t)c * 65536]);
  float* dst = (float*)(ws + ((mb >> 1) ? WS_M2 : WS_M1)) + (size_t)(mb & 1) * 65536 + ij;
  *dst = s;
}

// ---------------- k3: affinity = sigmoid(m1 @ m2) -> bf16 ---------------------
__global__ __launch_bounds__(256) void k3_aff(char* __restrict__ ws)
{
  const int j = threadIdx.x;
  const int i = blockIdx.x & 255;
  const int b = blockIdx.x >> 8;
  const float* m1 = (const float*)(ws + WS_M1) + (size_t)b * CC * CC;
  const float* m2 = (const float*)(ws + WS_M2) + (size_t)b * CC * CC;
  float z = 0.f;
  #pragma unroll 8
  for (int k = 0; k < 256; ++k)
    z = fmaf(m1[i*256 + k], m2[k*256 + j], z);
  float a = 1.f / (1.f + expf(-z));
  ((short*)(ws + WS_AFF))[(size_t)b*CC*CC + i*256 + j] = f2bf(a);
}

// ---------------- k4: out = gamma * (affinity @ V) + x ------------------------
__global__ __launch_bounds__(512, 4) void k4_out(
    const float* __restrict__ x, const float* __restrict__ gamma_p,
    char* __restrict__ ws, float* __restrict__ out)
{
  __shared__ short affS[256][72];  // rows i, 64-c chunk
  __shared__ short Vs[128][72];    // rows n, 64-c chunk (transposed stage)

  const int tid = threadIdx.x;
  const int n0 = blockIdx.x * 128;
  const int b  = blockIdx.y;
  const float gamma = gamma_p[0];
  const short* aff = (const short*)(ws + WS_AFF) + (size_t)b * CC * CC;
  const short* Vm  = (const short*)(ws + WS_V) + (size_t)b * NVOX * CC;

  const int lane = tid & 63, wid = tid >> 6;
  const int wi = wid >> 1, wn = wid & 1;
  const int lr = lane & 15, lg = lane >> 4;

  f32x4 acc[4][4];
  #pragma unroll
  for (int a = 0; a < 4; ++a)
    #pragma unroll
    for (int c = 0; c < 4; ++c) { f32x4 z = {0.f,0.f,0.f,0.f}; acc[a][c] = z; }

  for (int c0 = 0; c0 < 256; c0 += 64) {
    __syncthreads();
    #pragma unroll
    for (int it = 0; it < 4; ++it) {
      int idx = tid + 512 * it;
      int r = idx >> 3, c8 = (idx & 7) << 3;
      *(s16x8*)&affS[r][c8] = *(const s16x8*)&aff[(size_t)r * 256 + c0 + c8];
    }
    #pragma unroll
    for (int it = 0; it < 2; ++it) {
      int idx = tid + 512 * it;
      int t15 = idx & 15;
      int cc = idx >> 4, n8 = t15 << 3;
      s16x8 v = *(const s16x8*)&Vm[(size_t)(c0 + cc) * NVOX + n0 + n8];
      #pragma unroll
      for (int uu = 0; uu < 8; ++uu) {
        int u = (uu + t15) & 7;
        Vs[n8 + u][cc] = v[u];
      }
    }
    __syncthreads();
    #pragma unroll
    for (int ks = 0; ks < 2; ++ks) {
      s16x8 af[4], bv[4];
      #pragma unroll
      for (int mi = 0; mi < 4; ++mi)
        af[mi] = *(const s16x8*)&affS[wi*64 + mi*16 + lr][ks*32 + lg*8];
      #pragma unroll
      for (int nj = 0; nj < 4; ++nj)
        bv[nj] = *(const s16x8*)&Vs[wn*64 + nj*16 + lr][ks*32 + lg*8];
      #pragma unroll
      for (int mi = 0; mi < 4; ++mi)
        #pragma unroll
        for (int nj = 0; nj < 4; ++nj)
          acc[mi][nj] = __builtin_amdgcn_mfma_f32_16x16x32_bf16(
              bv[nj], af[mi], acc[mi][nj], 0, 0, 0);   // D = V^T·aff^T
    }
  }
  #pragma unroll
  for (int mi = 0; mi < 4; ++mi)
    #pragma unroll
    for (int nj = 0; nj < 4; ++nj) {
      int i = wi*64 + mi*16 + lr;
      int n = n0 + wn*64 + nj*16 + lg*4;
      size_t flat = (size_t)b * NVOX * CC + (size_t)i * NVOX + n;
      const float4 xv = *(const float4*)(x + flat);
      float4 o;
      o.x = gamma * acc[mi][nj][0] + xv.x;
      o.y = gamma * acc[mi][nj][1] + xv.y;
      o.z = gamma * acc[mi][nj][2] + xv.z;
      o.w = gamma * acc[mi][nj][3] + xv.w;
      *(float4*)(out + flat) = o;
    }
}

// ---------------- launcher ----------------------------------------------------
extern "C" void kernel_launch(void* const* d_in, const int* in_sizes, int n_in,
                              void* d_out, int out_size, void* d_ws, size_t ws_size,
                              hipStream_t stream)
{
  const float* x      = (const float*)d_in[0];
  const float* conv_w = (const float*)d_in[1];
  const float* conv_b = (const float*)d_in[2];
  const float* bn_s   = (const float*)d_in[3];
  const float* bn_o   = (const float*)d_in[4];
  const float* bn_m   = (const float*)d_in[5];
  const float* bn_v   = (const float*)d_in[6];
  const float* gamma  = (const float*)d_in[7];
  char*  ws  = (char*)d_ws;
  float* out = (float*)d_out;

  const bool part = ws_size >= WS_NEED_PART;

  k0_prep    <<<1024, 256, 0, stream>>>(conv_w, conv_b, bn_s, bn_o, bn_m, bn_v, ws);
  k1_branches<<<1024, 256, 0, stream>>>(x, ws);
  if (part) {
    k2_m1m2<1><<<dim3(64, 2, 2), 512, 0, stream>>>(ws);
    k25_reduce<<<1024, 256, 0, stream>>>(ws);
  } else {
    k2_m1m2<0><<<dim3(64, 2, 2), 512, 0, stream>>>(ws);
  }
  k3_aff     <<<512, 256, 0, stream>>>(ws);
  k4_out     <<<dim3(256, 2), 512, 0, stream>>>(x, gamma, ws, out);
}